// Round 7
// baseline (469.994 us; speedup 1.0000x reference)
//
#include <hip/hip_runtime.h>

#define NN 8192
#define SBS 512
#define NSB 16
#define LOG2E 1.44269504088896f

// ws ints: [0]=F_SUBDONE (monotone k*8+m+1); FR(k,w) per-(k,target) lines
#define FR(k,w) (32 + ((k)*8 + (w))*32)
// ws floats: partials [8192,16384) | cp[9][NN] [16384,90112) | s_arr [90112,98304)
#define PART_OFF 8192
#define CP_OFF   16384
#define NCPROW   9
#define SARR_OFF (CP_OFF + NCPROW * NN)

__device__ __forceinline__ float bcastf(float v, int lane) {
    return __int_as_float(__builtin_amdgcn_readlane(__float_as_int(v), lane));
}
__device__ __forceinline__ float sigm(float prelog) {   // pre already in log2e units
    return __builtin_amdgcn_rcpf(1.0f + __builtin_amdgcn_exp2f(-prelog));
}
__device__ __forceinline__ int ld_flag(const int* p) {
    return __hip_atomic_load(p, __ATOMIC_RELAXED, __HIP_MEMORY_SCOPE_AGENT);
}
__device__ __forceinline__ void st_rel(int* p, int v) {
    __hip_atomic_store(p, v, __ATOMIC_RELEASE, __HIP_MEMORY_SCOPE_AGENT);
}
__device__ __forceinline__ float ldf(const float* p) {
    return __hip_atomic_load(p, __ATOMIC_RELAXED, __HIP_MEMORY_SCOPE_AGENT);
}
__device__ __forceinline__ void stf(float* p, float v) {
    __hip_atomic_store(p, v, __ATOMIC_RELAXED, __HIP_MEMORY_SCOPE_AGENT);
}
// barrier that does NOT drain vmcnt (keeps streamed prefetch loads in flight)
#define LBAR() do { asm volatile("s_waitcnt lgkmcnt(0)\ns_barrier" ::: "memory"); \
                    __builtin_amdgcn_sched_barrier(0); } while (0)

__global__ void init_ws(int* wsi, float* wsf) {
    int i = blockIdx.x * 256 + threadIdx.x;   // grid 288*256 = 73728 = 9*NN
    if (i < 8192) wsi[i] = 0;
    wsf[CP_OFF + i] = 0.0f;
}

// ---------- solver WG (bid 0): 8 waves; wave w owns cols [k*512 + w*64, +64) ----------
__device__ void solver_fn(const float* __restrict__ W, const float* __restrict__ b,
                          const float* __restrict__ x, float* wsf, int* flags,
                          float* sdiag, float* spub, float* __restrict__ out, int k) {
    const int tid = threadIdx.x;
    const int w = tid >> 6, l = tid & 63;
    const int dj = tid >> 3, dc = (tid & 7) * 8;   // diag staging role
    const int J0 = k * SBS;
    const float* cp = wsf + CP_OFF;
    float* partials = wsf + PART_OFF;
    float* s_arr = wsf + SARR_OFF;

    auto load_diag = [&](int mm, float4& a, float4& bq) {
        if (dj < dc + 7) {   // skip chunks entirely at/below the diagonal
            const float* p = &W[(size_t)(J0 + mm*64 + dj) * NN + (J0 + mm*64 + dc)];
            a  = *(const float4*)p;
            bq = *(const float4*)(p + 4);
        } else {
            a = make_float4(0.f,0.f,0.f,0.f); bq = make_float4(0.f,0.f,0.f,0.f);
        }
    };
    auto write_diag = [&](int mm, float4 a, float4 bq) {
        float* dst = &sdiag[mm*4096 + dj*64 + dc];
        float v[8] = {a.x, a.y, a.z, a.w, bq.x, bq.y, bq.z, bq.w};
        #pragma unroll
        for (int e = 0; e < 8; ++e) dst[e] = (dj < dc + e) ? v[e] * LOG2E : 0.0f;
    };

    // ---- prologue: need-ordered issue ----
    const float x0 = x[0], x1 = x[1];
    float base = b[J0 + tid];
    #pragma unroll
    for (int r = 0; r < NCPROW; ++r) base += cp[r * NN + J0 + tid];

    // full dist-1 panel in registers: wave w folds source sub-block w-1 -> target w
    // (wave 0: source = prev block's sub 7, rows J0-64..J0-1)
    float p1[64];
    const int srow = J0 + ((w == 0) ? -64 : (w - 1) * 64);
    if (k > 0 || w > 0) {
        #pragma unroll
        for (int r = 0; r < 64; ++r)
            p1[r] = W[(size_t)(srow + r) * NN + (J0 + w*64 + l)];
    }
    float4 dA[2], dB[2];
    load_diag(0, dA[0], dB[0]);
    load_diag(1, dA[1], dB[1]);
    if (k > 0 && w == 0) spub[512 + l] = s_arr[J0 - 64 + l];  // prev block's sub-7 s
    write_diag(0, dA[0], dB[0]);
    float part_w = 0.0f;   // preloaded helper partial for this wave's chain
    LBAR();

    #pragma unroll
    for (int m = 0; m < 8; ++m) {
        if (w == m) {
            // ---- dist-1 fold from registers + LDS broadcast (prev sub's s) ----
            float rsum = 0.0f;
            if (m > 0 || k > 0) {
                const int soff = (m == 0) ? 512 : (m - 1) * 64;
                #pragma unroll
                for (int r4 = 0; r4 < 16; ++r4) {
                    float4 sv = *(const float4*)&spub[soff + r4*4];
                    rsum += p1[r4*4+0]*sv.x + p1[r4*4+1]*sv.y
                          + p1[r4*4+2]*sv.z + p1[r4*4+3]*sv.w;
                }
            }
            if (m < 7)      write_diag(m + 1, dA[(m+1) & 1], dB[(m+1) & 1]);
            if (m + 2 <= 7) load_diag(m + 2, dA[(m+2) & 1], dB[(m+2) & 1]);
            float acc = (base + rsum + part_w) * LOG2E;
            float smine = 0.0f;
            const bool first = (k == 0) && (m == 0);
            #pragma unroll
            for (int j = 0; j < 64; ++j) {
                const float pre = bcastf(acc, j);
                float s;
                if (first && j == 0)      s = x0;
                else if (first && j == 1) s = x1;
                else                      s = sigm(pre);
                acc += sdiag[m*4096 + j*64 + l] * s;   // 0 for j>=l
                if (l == j) smine = s;
            }
            spub[m*64 + l] = smine;
            if (m == 7) stf(&s_arr[J0 + 448 + l], smine);   // next launch reads it
            if (k == NSB - 1 && m == 7 && l == 63) out[0] = smine;
        } else {
            // next chain wave: pre-poll helper flag + preload partial (hidden)
            if (w == m + 1 && (w >= 2 || (w == 1 && k > 0))) {
                const int* fl = &flags[FR(k, w)];
                while (ld_flag(fl) == 0) {}
                __builtin_amdgcn_fence(__ATOMIC_ACQUIRE, "agent");
                part_w = ldf(&partials[((size_t)k*8 + w)*64 + l]);
            }
            // store-wave: publish sub m-1 globally + release flag (off chain path)
            if (m >= 1 && w == ((m + 3) & 7)) {
                float val = spub[(m-1)*64 + l];
                stf(&s_arr[J0 + (m-1)*64 + l], val);
                if (l == 0) st_rel(&flags[0], k*8 + m);
                __builtin_amdgcn_sched_barrier(0);
            }
            if (m < 7)      write_diag(m + 1, dA[(m+1) & 1], dB[(m+1) & 1]);
            if (m + 2 <= 7) load_diag(m + 2, dA[(m+2) & 1], dB[(m+2) & 1]);
        }
        LBAR();
    }
}

// ---------- helper WG (bids 1..7): target TW; folds (k-1,7) + in-block 0..TW-2 ----------
template <int TW>
__device__ void helper_fn(const float* __restrict__ W, float* wsf, int* flags,
                          float (*redh)[64], int k) {
    const int tid = threadIdx.x, g = tid >> 6, l = tid & 63;
    float* partials = wsf + PART_OFF;
    const float* s_arr = wsf + SARR_OFF;
    const int J0 = k * SBS;
    const int col = J0 + TW*64 + l;
    float part = 0.0f;

    if (k > 0) {   // cross-block source (k-1, sub 7): ready at launch start
        float wv[8], sv[8];
        #pragma unroll
        for (int r = 0; r < 8; ++r) {
            wv[r] = W[(size_t)(J0 - 64 + g*8 + r) * NN + col];
            sv[r] = s_arr[J0 - 64 + g*8 + r];
        }
        #pragma unroll
        for (int r = 0; r < 8; ++r) part += wv[r] * sv[r];
    }
    if constexpr (TW >= 2) {
        float pr[TW - 1][8];
        #pragma unroll
        for (int m = 0; m <= TW - 2; ++m)
            #pragma unroll
            for (int r = 0; r < 8; ++r)
                pr[m][r] = W[(size_t)(J0 + m*64 + g*8 + r) * NN + col];
        #pragma unroll
        for (int m = 0; m <= TW - 2; ++m) {
            if (tid < 64) {
                while (ld_flag(&flags[0]) < k*8 + m + 1) __builtin_amdgcn_s_sleep(1);
            }
            __syncthreads();
            __builtin_amdgcn_fence(__ATOMIC_ACQUIRE, "agent");
            #pragma unroll
            for (int r = 0; r < 8; ++r)
                part += pr[m][r] * ldf(&s_arr[J0 + m*64 + g*8 + r]);
        }
    }
    redh[g][l] = part;
    __syncthreads();
    if (tid < 64) {
        float tot = 0.0f;
        #pragma unroll
        for (int g2 = 0; g2 < 8; ++g2) tot += redh[g2][tid];
        stf(&partials[((size_t)k*8 + TW)*64 + tid], tot);
    }
    __syncthreads();
    if (tid == 0) st_rel(&flags[FR(k, TW)], 1);
}

// ---------- near WG (bids 8..15): block k sources 0..6 -> block k+1 target t ----------
__device__ void near_fn(const float* __restrict__ W, float* wsf, int* flags,
                        float (*redh)[64], int t, int k) {
    const int tid = threadIdx.x, g = tid >> 6, l = tid & 63;
    const int col = (k+1)*SBS + t*64 + l;
    const float* s_arr = wsf + SARR_OFF;
    float* cp = wsf + CP_OFF;

    float pr[7][8];
    #pragma unroll
    for (int m = 0; m < 7; ++m)
        #pragma unroll
        for (int r = 0; r < 8; ++r)
            pr[m][r] = W[(size_t)(k*SBS + m*64 + g*8 + r) * NN + col];

    float part = 0.0f;
    #pragma unroll
    for (int m = 0; m < 7; ++m) {
        if (tid < 64) {
            while (ld_flag(&flags[0]) < k*8 + m + 1) __builtin_amdgcn_s_sleep(4);
        }
        __syncthreads();
        __builtin_amdgcn_fence(__ATOMIC_ACQUIRE, "agent");
        #pragma unroll
        for (int r = 0; r < 8; ++r)
            part += pr[m][r] * ldf(&s_arr[k*SBS + m*64 + g*8 + r]);
    }
    redh[g][l] = part;
    __syncthreads();
    if (g == 0) {
        float tot = 0.0f;
        #pragma unroll
        for (int g2 = 0; g2 < 8; ++g2) tot += redh[g2][l];
        cp[8 * NN + col] = tot;           // 9th accumulator row: near-only, fresh write
    }
}

// ---------- bulk WG (bids 16+): source block k-1 -> targets k+1..15 (data ready) ----------
__device__ void bulk_fn(const float* __restrict__ W, float* wsf,
                        float* ssh, int idx, int k) {
    const int tid = threadIdx.x;
    const int rc = idx & 7, cg = idx >> 3;
    const int row0 = (k-1)*SBS + rc*64;
    const int col = (k+1)*SBS + cg*SBS + tid;
    const float* s_arr = wsf + SARR_OFF;
    float* cp = wsf + CP_OFF;

    if (tid < 64) ssh[tid] = s_arr[row0 + tid];
    __syncthreads();
    const float* wp = W + (size_t)row0 * NN + col;
    float a0 = 0.f, a1 = 0.f, a2 = 0.f, a3 = 0.f;
    #pragma unroll
    for (int i = 0; i < 64; i += 4) {
        a0 += wp[(size_t)(i + 0) * NN] * ssh[i + 0];
        a1 += wp[(size_t)(i + 1) * NN] * ssh[i + 1];
        a2 += wp[(size_t)(i + 2) * NN] * ssh[i + 2];
        a3 += wp[(size_t)(i + 3) * NN] * ssh[i + 3];
    }
    cp[rc * NN + col] += (a0 + a1) + (a2 + a3);   // single writer per (rc,col) per launch
}

__global__ void __launch_bounds__(512, 1) mega_kernel(
    const float* __restrict__ W, const float* __restrict__ b,
    const float* __restrict__ x, float* wsf, int* flags,
    float* __restrict__ out, int k)
{
    __shared__ float sdiag[8 * 4096];   // [m][j][l], pre-scaled by LOG2E, 0 for j>=l
    __shared__ float spub[576];         // this block's s; [512..575] = prev block sub-7
    __shared__ float redh[8][64];       // helper/near reduction; bulk s staging
    const int bid = blockIdx.x;
    if (bid == 0) {
        solver_fn(W, b, x, wsf, flags, sdiag, spub, out, k);
    } else if (bid <= 7) {
        switch (bid) {
            case 1: helper_fn<1>(W, wsf, flags, redh, k); break;
            case 2: helper_fn<2>(W, wsf, flags, redh, k); break;
            case 3: helper_fn<3>(W, wsf, flags, redh, k); break;
            case 4: helper_fn<4>(W, wsf, flags, redh, k); break;
            case 5: helper_fn<5>(W, wsf, flags, redh, k); break;
            case 6: helper_fn<6>(W, wsf, flags, redh, k); break;
            case 7: helper_fn<7>(W, wsf, flags, redh, k); break;
        }
    } else if (bid <= 15) {
        near_fn(W, wsf, flags, redh, bid - 8, k);      // launched only for k<15
    } else {
        bulk_fn(W, wsf, &redh[0][0], bid - 16, k);     // launched only for k>=1
    }
}

extern "C" void kernel_launch(void* const* d_in, const int* in_sizes, int n_in,
                              void* d_out, int out_size, void* d_ws, size_t ws_size,
                              hipStream_t stream) {
    const float* x = (const float*)d_in[0];
    const float* W = (const float*)d_in[1];
    const float* b = (const float*)d_in[2];
    float* out = (float*)d_out;
    float* wsf = (float*)d_ws;
    int* wsi   = (int*)d_ws;

    init_ws<<<dim3(288), dim3(256), 0, stream>>>(wsi, wsf);
    for (int k = 0; k < NSB; ++k) {
        int nb;
        if (k == 0)            nb = 16;                 // solver + 7 helpers + 8 near
        else if (k == NSB - 1) nb = 8;                  // solver + 7 helpers
        else                   nb = 16 + 8 * (15 - k);  // + bulk (src k-1 -> k+1..15)
        mega_kernel<<<dim3(nb), dim3(512), 0, stream>>>(W, b, x, wsf, wsi, out, k);
    }
}